// Round 1
// baseline (104.217 us; speedup 1.0000x reference)
//
#include <hip/hip_runtime.h>

// Problem constants (fixed by the reference):
//   x: (B=2, C=64, H=16, W=64) fp32; S = H*W = 1024; heads g=64, per-head c=1.
//   scores[s,t] = q_s * k_t / 8 ; softmax over t ; o_s = sum_t p_st * v_t
#define BB   2
#define CC   64
#define SS   1024
#define SCL  0.125f   // 1/sqrt(64)

// ---------------- Kernel 1: fused QKV projection (1x1 convs) ----------------
// One block per (b, o, s-chunk-of-256). Q/K/V[b,o,s] = dot(W[o,:], x[b,:,s]) + b[o]
__global__ __launch_bounds__(256) void qkv_kernel(
    const float* __restrict__ x,
    const float* __restrict__ Wq, const float* __restrict__ bq,
    const float* __restrict__ Wk, const float* __restrict__ bk,
    const float* __restrict__ Wv, const float* __restrict__ bv,
    float* __restrict__ Q, float* __restrict__ K, float* __restrict__ V)
{
    const int bid = blockIdx.x;          // [0, 512)
    const int b   = bid >> 8;            // / 256
    const int rem = bid & 255;
    const int o   = rem >> 2;            // channel / head index
    const int sc  = rem & 3;
    const int s   = (sc << 8) + threadIdx.x;

    __shared__ float wq[CC], wk[CC], wv[CC];
    if (threadIdx.x < CC) {
        wq[threadIdx.x] = Wq[o * CC + threadIdx.x];
        wk[threadIdx.x] = Wk[o * CC + threadIdx.x];
        wv[threadIdx.x] = Wv[o * CC + threadIdx.x];
    }
    __syncthreads();

    const float* xb = x + b * CC * SS + s;
    float qa = bq[o], ka = bk[o], va = bv[o];
    #pragma unroll 8
    for (int c = 0; c < CC; ++c) {
        float xv = xb[c * SS];
        qa = fmaf(wq[c], xv, qa);
        ka = fmaf(wk[c], xv, ka);
        va = fmaf(wv[c], xv, va);
    }
    const int idx = (b * CC + o) * SS + s;
    Q[idx] = qa; K[idx] = ka; V[idx] = va;
}

// ---------------- Kernel 2: per-head rank-1 attention ----------------
// One block per (head, s-chunk-of-256). c==1, so for each query position s:
//   arg_t = p * k_t  with p = q_s/8 ; rowmax = p>=0 ? p*kmax : p*kmin
//   o_s = sum_t exp(arg_t - rowmax) * v_t / sum_t exp(arg_t - rowmax)
__global__ __launch_bounds__(256) void attn_kernel(
    const float* __restrict__ Q, const float* __restrict__ K,
    const float* __restrict__ V, float* __restrict__ O)
{
    const int bid  = blockIdx.x;   // [0, 512) = 128 heads * 4 chunks
    const int head = bid >> 2;
    const int sc   = bid & 3;

    __shared__ float ks[SS], vs[SS];
    __shared__ float wmax[4], wmin[4];

    const float* Kh = K + head * SS;
    const float* Vh = V + head * SS;

    float lmax = -1e30f, lmin = 1e30f;
    for (int i = threadIdx.x; i < SS; i += 256) {
        float kv = Kh[i];
        ks[i] = kv;
        vs[i] = Vh[i];
        lmax = fmaxf(lmax, kv);
        lmin = fminf(lmin, kv);
    }
    // wave(64) shuffle reduce, then combine 4 waves through LDS
    #pragma unroll
    for (int off = 32; off; off >>= 1) {
        lmax = fmaxf(lmax, __shfl_down(lmax, off, 64));
        lmin = fminf(lmin, __shfl_down(lmin, off, 64));
    }
    const int lane = threadIdx.x & 63, wid = threadIdx.x >> 6;
    if (lane == 0) { wmax[wid] = lmax; wmin[wid] = lmin; }
    __syncthreads();
    const float kmax = fmaxf(fmaxf(wmax[0], wmax[1]), fmaxf(wmax[2], wmax[3]));
    const float kmin = fminf(fminf(wmin[0], wmin[1]), fminf(wmin[2], wmin[3]));

    const int s = (sc << 8) + threadIdx.x;
    const float p = Q[head * SS + s] * SCL;
    const float m = (p >= 0.f) ? p * kmax : p * kmin;   // exact row max

    float se = 0.f, sev = 0.f;
    #pragma unroll 4
    for (int t = 0; t < SS; ++t) {
        float e = __expf(fmaf(p, ks[t], -m));   // LDS broadcast reads: conflict-free
        se  += e;
        sev  = fmaf(e, vs[t], sev);
    }
    O[head * SS + s] = sev / se;
}

// ---------------- Kernel 3: output projection + residual ----------------
// out[b,o,s] = x[b,o,s] + dot(Wo[o,:], O[b,:,s]) + bo[o]
__global__ __launch_bounds__(256) void proj_kernel(
    const float* __restrict__ x, const float* __restrict__ O,
    const float* __restrict__ Wo, const float* __restrict__ bo,
    float* __restrict__ out)
{
    const int bid = blockIdx.x;
    const int b   = bid >> 8;
    const int rem = bid & 255;
    const int o   = rem >> 2;
    const int sc  = rem & 3;
    const int s   = (sc << 8) + threadIdx.x;

    __shared__ float wo[CC];
    if (threadIdx.x < CC) wo[threadIdx.x] = Wo[o * CC + threadIdx.x];
    __syncthreads();

    const float* Ob = O + b * CC * SS + s;
    float acc = bo[o];
    #pragma unroll 8
    for (int c = 0; c < CC; ++c)
        acc = fmaf(wo[c], Ob[c * SS], acc);

    const int idx = (b * CC + o) * SS + s;
    out[idx] = x[idx] + acc;
}

extern "C" void kernel_launch(void* const* d_in, const int* in_sizes, int n_in,
                              void* d_out, int out_size, void* d_ws, size_t ws_size,
                              hipStream_t stream) {
    const float* x  = (const float*)d_in[0];
    const float* Wq = (const float*)d_in[1];
    const float* bq = (const float*)d_in[2];
    const float* Wk = (const float*)d_in[3];
    const float* bk = (const float*)d_in[4];
    const float* Wv = (const float*)d_in[5];
    const float* bv = (const float*)d_in[6];
    const float* Wo = (const float*)d_in[7];
    const float* bo = (const float*)d_in[8];
    float* out = (float*)d_out;

    const int N = BB * CC * SS;        // 131072 elements per tensor
    float* Q = (float*)d_ws;
    float* K = Q + N;
    float* V = K + N;
    float* O = V + N;                  // total 2 MB of workspace

    qkv_kernel <<<512, 256, 0, stream>>>(x, Wq, bq, Wk, bk, Wv, bv, Q, K, V);
    attn_kernel<<<512, 256, 0, stream>>>(Q, K, V, O);
    proj_kernel<<<512, 256, 0, stream>>>(x, O, Wo, bo, out);
}